// Round 5
// baseline (227.960 us; speedup 1.0000x reference)
//
#include <hip/hip_runtime.h>
#include <hip/hip_bf16.h>
#include <math.h>

#define B_ 32
#define T_ 2000
#define DE_ 512
#define DD_ 1024
#define A_ 128
#define FN_ 32
#define FS_ 16
#define KW_ (2*FS_+1)   // 33

typedef __bf16 bf16x8 __attribute__((ext_vector_type(8)));
typedef __bf16 bf16x4 __attribute__((ext_vector_type(4)));
typedef float f32x4 __attribute__((ext_vector_type(4)));

#define BT 64            // t-rows per score block
#define LSTR 40          // loc tile LDS stride (bf16)

// async global->LDS, 16 B per lane; dest = lds base (wave-uniform) + lane*16
__device__ __forceinline__ void load_lds16(const void* g, void* l) {
    __builtin_amdgcn_global_load_lds(
        (const __attribute__((address_space(1))) unsigned int*)g,
        (__attribute__((address_space(3))) unsigned int*)l, 16, 0, 0);
}

// ---------------------------------------------------------------------------
// Kernel 1: prep.
//  blocks   0..63 : enc_w/att_w fp32->bf16
//  blocks  64..191: pdec[b][a] = att_b[a] + input_dec[b] . dec_w[a]
//  blocks 192..208: zero ctx_un (16384 f) + denom (32 f)
// ---------------------------------------------------------------------------
__global__ __launch_bounds__(256) void prep_kernel(
    const float* __restrict__ enc_w, const float* __restrict__ att_w,
    const float* __restrict__ input_dec, const float* __restrict__ dec_w,
    const float* __restrict__ att_b,
    __bf16* __restrict__ enc_bf, __bf16* __restrict__ att_bf,
    float* __restrict__ pdec, float* __restrict__ ctx_un /* denom follows */)
{
    int bx = blockIdx.x, tid = threadIdx.x;
    if (bx < 64) {
        int i = bx * 256 + tid;                         // float4 index
        float4 v = ((const float4*)enc_w)[i];
        bf16x4 o;
        o[0] = (__bf16)v.x; o[1] = (__bf16)v.y; o[2] = (__bf16)v.z; o[3] = (__bf16)v.w;
        *(bf16x4*)(enc_bf + (size_t)i * 4) = o;
        if (i < (A_ * FN_) / 4) {
            float4 w = ((const float4*)att_w)[i];
            bf16x4 p;
            p[0] = (__bf16)w.x; p[1] = (__bf16)w.y; p[2] = (__bf16)w.z; p[3] = (__bf16)w.w;
            *(bf16x4*)(att_bf + (size_t)i * 4) = p;
        }
    } else if (bx < 192) {
        int pb = bx - 64;                               // 0..127
        int b  = pb >> 2;
        int a0 = (pb & 3) * 32;
        int al = tid >> 3;                              // 0..31
        int kg = tid & 7;                               // 0..7
        int a  = a0 + al;
        const float4* w = (const float4*)(dec_w + (size_t)a * DD_);
        const float4* x = (const float4*)(input_dec + (size_t)b * DD_);
        float acc = 0.f;
        #pragma unroll 8
        for (int j = 0; j < 32; j++) {
            int i4 = kg + j * 8;
            float4 wv = w[i4], xv = x[i4];
            acc += wv.x * xv.x + wv.y * xv.y + wv.z * xv.z + wv.w * xv.w;
        }
        acc += __shfl_xor(acc, 1, 64);
        acc += __shfl_xor(acc, 2, 64);
        acc += __shfl_xor(acc, 4, 64);
        if (kg == 0) pdec[b * A_ + a] = acc + att_b[a];
    } else {
        int idx = (bx - 192) * 256 + tid;               // float4 index
        if (idx < (B_ * DE_ + B_) / 4 + 1)              // 16416 floats
            ((float4*)ctx_un)[idx] = make_float4(0.f, 0.f, 0.f, 0.f);
    }
}

// ---------------------------------------------------------------------------
// Kernel 2: score + context partials. One block = (b, 64 t-rows).
// Early-exit for fully-masked blocks. Single-barrier ping-pong K-loop
// (KC=32 halves of a 16 KB LDS B buffer) with A-register prefetch: DMA and
// A loads for chunk k+1 issue after barrier k, drain at barrier k+1 (hidden
// behind chunk-k MFMA + ds_reads). Max-free softmax (M = sum|out_w|);
// block accumulates its own 64x512 tile into ctx_un + sum(w) into denom.
// ---------------------------------------------------------------------------
__global__ __launch_bounds__(256, 4) void score_kernel(
    const float* __restrict__ input_enc, const __bf16* __restrict__ enc_bf,
    const float* __restrict__ prev_att,  const float* __restrict__ conv_w,
    const __bf16* __restrict__ att_bf,   const float* __restrict__ pdec,
    const float* __restrict__ out_w,     const int* __restrict__ lengths,
    float* __restrict__ wbuf, float* __restrict__ ctx_un,
    float* __restrict__ denom)
{
    __shared__ __align__(16) char Bt[16384];     // 2 halves x (128 rows x 32 k bf16)
    __shared__ float pa_s[BT + 2 * FS_];
    __shared__ float cw_s[KW_ * FN_];
    __shared__ __align__(16) __bf16 loc_s[BT * LSTR];
    __shared__ __align__(16) float w_s[BT];

    const int tid = threadIdx.x;
    const int b  = blockIdx.y;
    const int t0 = blockIdx.x * BT;
    const int len = lengths[b];

    // ---- early exit: fully masked block -> w = 0 for all rows ----
    if (t0 >= len) {
        int t = t0 + tid;
        if (tid < BT && t < T_) wbuf[b * T_ + t] = 0.f;
        return;
    }

    const int lane = tid & 63;
    const int wv   = tid >> 6;
    const int col  = lane & 15;
    const int grp  = lane >> 4;
    const int rowb = wv * 16 + col;
    const int t_row = t0 + rowb;
    const int t_clamp = t_row < T_ ? t_row : T_ - 1;
    const float* arow = input_enc + ((size_t)(b * T_ + t_clamp)) * DE_ + grp * 8;

    // ---- issue chunk-0 staging + A prefetch immediately (hidden by conv) ----
    // stage: slot s covers row r = s>>2, phys 16B-chunk cp = s&3;
    // source logical chunk c = cp ^ (r&3)  (XOR bank swizzle)
    #pragma unroll
    for (int j = 0; j < 2; j++) {
        int s  = j * 256 + tid;
        int r  = s >> 2;
        int c  = (s & 3) ^ (r & 3);
        load_lds16(enc_bf + (size_t)r * DE_ + c * 8,
                   Bt + j * 4096 + wv * 1024);
    }
    float4 p0 = *(const float4*)(arow);
    float4 p1 = *(const float4*)(arow + 4);

    for (int j = tid; j < BT + 2 * FS_; j += 256) {
        int t = t0 - FS_ + j;
        pa_s[j] = (t >= 0 && t < T_) ? prev_att[b * T_ + t] : 0.f;
    }
    for (int idx = tid; idx < FN_ * KW_; idx += 256) {
        int f = idx / KW_, k = idx % KW_;
        cw_s[k * FN_ + f] = conv_w[idx];
    }
    __syncthreads();

    {   // conv -> loc (bf16)
        int f = tid & 31, r0 = tid >> 5;
        for (int r = r0; r < BT; r += 8) {
            float acc = 0.f;
            #pragma unroll
            for (int k = 0; k < KW_; k++) acc += pa_s[r + k] * cw_s[k * FN_ + f];
            loc_s[r * LSTR + f] = (__bf16)acc;
        }
    }
    __syncthreads();

    f32x4 acc[8];
    const f32x4 zero = (f32x4){0.f, 0.f, 0.f, 0.f};

    {   // loc-projection MFMA (K=32=FN)
        bf16x8 afrag = *(const bf16x8*)(loc_s + rowb * LSTR + grp * 8);
        #pragma unroll
        for (int i = 0; i < 8; i++) {
            bf16x8 bfrag = *(const bf16x8*)(att_bf + (size_t)(i * 16 + col) * FN_ + grp * 8);
            acc[i] = __builtin_amdgcn_mfma_f32_16x16x32_bf16(afrag, bfrag, zero, 0, 0, 0);
        }
    }

    const int dsoff = (grp ^ (col & 3)) * 16;    // swizzled phys chunk for reads

    #pragma unroll
    for (int k = 0; k < 16; k++) {
        __syncthreads();                          // half(k&1) staged; prior reads done
        float4 n0, n1;
        if (k < 15) {
            int kc_next = (k + 1) * 32;
            char* half = Bt + (((k + 1) & 1) << 13);
            #pragma unroll
            for (int j = 0; j < 2; j++) {
                int s  = j * 256 + tid;
                int r  = s >> 2;
                int c  = (s & 3) ^ (r & 3);
                load_lds16(enc_bf + (size_t)r * DE_ + kc_next + c * 8,
                           half + j * 4096 + wv * 1024);
            }
            n0 = *(const float4*)(arow + kc_next);
            n1 = *(const float4*)(arow + kc_next + 4);
        }
        bf16x8 af;
        af[0] = (__bf16)p0.x; af[1] = (__bf16)p0.y;
        af[2] = (__bf16)p0.z; af[3] = (__bf16)p0.w;
        af[4] = (__bf16)p1.x; af[5] = (__bf16)p1.y;
        af[6] = (__bf16)p1.z; af[7] = (__bf16)p1.w;
        const char* half = Bt + ((k & 1) << 13);
        #pragma unroll
        for (int i = 0; i < 8; i++) {
            bf16x8 bfrag = *(const bf16x8*)(half + (i * 16 + col) * 64 + dsoff);
            acc[i] = __builtin_amdgcn_mfma_f32_16x16x32_bf16(af, bfrag, acc[i], 0, 0, 0);
        }
        p0 = n0; p1 = n1;
    }

    // epilogue: s = tanh(acc + bias) . out_w over a; M = sum|out_w|
    float s[4] = {0.f, 0.f, 0.f, 0.f};
    float Mabs = 0.f;
    #pragma unroll
    for (int i = 0; i < 8; i++) {
        int a = i * 16 + col;
        float ow = out_w[a];
        Mabs += fabsf(ow);
        float bias = pdec[b * A_ + a];
        #pragma unroll
        for (int r = 0; r < 4; r++) {
            float v = acc[i][r] + bias;
            v = fminf(fmaxf(v, -15.f), 15.f);
            float e = __expf(2.f * v);
            s[r] += ow * ((e - 1.f) / (e + 1.f));
        }
    }
    #pragma unroll
    for (int r = 0; r < 4; r++) {
        s[r] += __shfl_xor(s[r], 1, 64);
        s[r] += __shfl_xor(s[r], 2, 64);
        s[r] += __shfl_xor(s[r], 4, 64);
        s[r] += __shfl_xor(s[r], 8, 64);
    }
    Mabs += __shfl_xor(Mabs, 1, 64);
    Mabs += __shfl_xor(Mabs, 2, 64);
    Mabs += __shfl_xor(Mabs, 4, 64);
    Mabs += __shfl_xor(Mabs, 8, 64);    // same value & rounding in every wave

    if (col == 0) {
        int tb = wv * 16 + grp * 4;              // block-local, multiple of 4
        float4 wvec;
        float* wp = &wvec.x;
        #pragma unroll
        for (int r = 0; r < 4; r++) {
            int t = t0 + tb + r;
            wp[r] = (t < len) ? __expf(s[r] - Mabs) : 0.f;
        }
        *(float4*)(w_s + tb) = wvec;
        if (t0 + tb < T_) *(float4*)(wbuf + b * T_ + t0 + tb) = wvec;
    }
    __syncthreads();

    // denominator partial (wave 0)
    if (tid < 64) {
        float w = w_s[tid];
        w += __shfl_xor(w, 1, 64);
        w += __shfl_xor(w, 2, 64);
        w += __shfl_xor(w, 4, 64);
        w += __shfl_xor(w, 8, 64);
        w += __shfl_xor(w, 16, 64);
        w += __shfl_xor(w, 32, 64);
        if (tid == 0) atomicAdd(&denom[b], w);
    }

    // context partial (tile rows L2/L3-hot from the GEMM reads)
    int n_eff = len - t0;
    if (n_eff > BT) n_eff = BT;
    {
        int tg = tid >> 7;                       // 0,1: interleaved t-halves
        int d0 = (tid & 127) * 4;
        const float* ebase = input_enc + ((size_t)(b * T_ + t0)) * DE_ + d0;
        float cx = 0.f, cy = 0.f, cz = 0.f, cw = 0.f;
        #pragma unroll 4
        for (int t = tg; t < n_eff; t += 2) {
            float w = w_s[t];
            float4 v = *(const float4*)(ebase + (size_t)t * DE_);
            cx += w * v.x; cy += w * v.y; cz += w * v.z; cw += w * v.w;
        }
        atomicAdd(&ctx_un[b * DE_ + d0 + 0], cx);
        atomicAdd(&ctx_un[b * DE_ + d0 + 1], cy);
        atomicAdd(&ctx_un[b * DE_ + d0 + 2], cz);
        atomicAdd(&ctx_un[b * DE_ + d0 + 3], cw);
    }
}

// ---------------------------------------------------------------------------
// Kernel 3: finalize. blocks 0..63: att = wbuf/denom; 64..79: ctx = ctx_un/denom
// ---------------------------------------------------------------------------
__global__ __launch_bounds__(256) void finalize_kernel(
    const float* __restrict__ wbuf, const float* __restrict__ ctx_un,
    const float* __restrict__ denom, float* __restrict__ out)
{
    int bx = blockIdx.x, tid = threadIdx.x;
    if (bx < 64) {
        int i4 = bx * 256 + tid;
        if (i4 < (B_ * T_) / 4) {
            int b = i4 / (T_ / 4);
            float inv = 1.f / denom[b];
            float4 w = ((const float4*)wbuf)[i4];
            w.x *= inv; w.y *= inv; w.z *= inv; w.w *= inv;
            ((float4*)(out + B_ * DE_))[i4] = w;
        }
    } else {
        int j = (bx - 64) * 256 + tid;          // 0..4095
        int b = j / (DE_ / 4);
        float inv = 1.f / denom[b];
        float4 c = ((const float4*)ctx_un)[j];
        c.x *= inv; c.y *= inv; c.z *= inv; c.w *= inv;
        ((float4*)out)[j] = c;
    }
}

// ---------------------------------------------------------------------------
extern "C" void kernel_launch(void* const* d_in, const int* in_sizes, int n_in,
                              void* d_out, int out_size, void* d_ws, size_t ws_size,
                              hipStream_t stream)
{
    const float* input_enc   = (const float*)d_in[0];
    const int*   enc_lengths = (const int*)d_in[1];
    const float* input_dec   = (const float*)d_in[2];
    const float* prev_att    = (const float*)d_in[3];
    const float* conv_w      = (const float*)d_in[4];
    const float* enc_w       = (const float*)d_in[5];
    const float* dec_w       = (const float*)d_in[6];
    const float* att_w       = (const float*)d_in[7];
    const float* att_b       = (const float*)d_in[8];
    const float* out_w       = (const float*)d_in[9];

    float* out = (float*)d_out;                 // [0:B*DE) context, [B*DE:) att_weight
    char* ws = (char*)d_ws;
    float*  pdec   = (float*)ws;                              // 4096 f   (16384 B)
    float*  wbuf   = (float*)(ws + 16384);                    // 64000 f  (256000 B)
    __bf16* enc_bf = (__bf16*)(ws + 272384);                  // A*DE bf16 (131072 B)
    __bf16* att_bf = (__bf16*)(ws + 403456);                  // A*FN bf16 (8192 B)
    float*  ctx_un = (float*)(ws + 411648);                   // 16384 f  (65536 B)
    float*  denom  = (float*)(ws + 477184);                   // 32 f (contiguous w/ ctx_un)

    prep_kernel<<<209, 256, 0, stream>>>(enc_w, att_w, input_dec, dec_w, att_b,
                                         enc_bf, att_bf, pdec, ctx_un);

    dim3 sgrid((T_ + BT - 1) / BT, B_);
    score_kernel<<<sgrid, 256, 0, stream>>>(input_enc, enc_bf, prev_att, conv_w,
                                            att_bf, pdec, out_w, enc_lengths,
                                            wbuf, ctx_un, denom);

    finalize_kernel<<<80, 256, 0, stream>>>(wbuf, ctx_un, denom, out);
}

// Round 6
// 227.266 us; speedup vs baseline: 1.0031x; 1.0031x over previous
//
#include <hip/hip_runtime.h>
#include <hip/hip_bf16.h>
#include <math.h>

#define B_ 32
#define T_ 2000
#define DE_ 512
#define DD_ 1024
#define A_ 128
#define FN_ 32
#define FS_ 16
#define KW_ (2*FS_+1)   // 33

typedef __bf16 bf16x8 __attribute__((ext_vector_type(8)));
typedef __bf16 bf16x4 __attribute__((ext_vector_type(4)));
typedef float f32x4 __attribute__((ext_vector_type(4)));

#define BT 64            // t-rows per score block

// async global->LDS, 16 B per lane; dest = lds base (wave-uniform) + lane*16
__device__ __forceinline__ void load_lds16(const void* g, void* l) {
    __builtin_amdgcn_global_load_lds(
        (const __attribute__((address_space(1))) unsigned int*)g,
        (__attribute__((address_space(3))) unsigned int*)l, 16, 0, 0);
}

// ---------------------------------------------------------------------------
// Kernel 1: prep.
//  blocks   0..63 : enc_w/att_w fp32->bf16
//  blocks  64..191: pdec[b][a] = att_b[a] + input_dec[b] . dec_w[a]
//  blocks 192..208: zero ctx_un (16384 f) + denom (32 f)
// ---------------------------------------------------------------------------
__global__ __launch_bounds__(256) void prep_kernel(
    const float* __restrict__ enc_w, const float* __restrict__ att_w,
    const float* __restrict__ input_dec, const float* __restrict__ dec_w,
    const float* __restrict__ att_b,
    __bf16* __restrict__ enc_bf, __bf16* __restrict__ att_bf,
    float* __restrict__ pdec, float* __restrict__ ctx_un /* denom follows */)
{
    int bx = blockIdx.x, tid = threadIdx.x;
    if (bx < 64) {
        int i = bx * 256 + tid;                         // float4 index
        float4 v = ((const float4*)enc_w)[i];
        bf16x4 o;
        o[0] = (__bf16)v.x; o[1] = (__bf16)v.y; o[2] = (__bf16)v.z; o[3] = (__bf16)v.w;
        *(bf16x4*)(enc_bf + (size_t)i * 4) = o;
        if (i < (A_ * FN_) / 4) {
            float4 w = ((const float4*)att_w)[i];
            bf16x4 p;
            p[0] = (__bf16)w.x; p[1] = (__bf16)w.y; p[2] = (__bf16)w.z; p[3] = (__bf16)w.w;
            *(bf16x4*)(att_bf + (size_t)i * 4) = p;
        }
    } else if (bx < 192) {
        int pb = bx - 64;                               // 0..127
        int b  = pb >> 2;
        int a0 = (pb & 3) * 32;
        int al = tid >> 3;                              // 0..31
        int kg = tid & 7;                               // 0..7
        int a  = a0 + al;
        const float4* w = (const float4*)(dec_w + (size_t)a * DD_);
        const float4* x = (const float4*)(input_dec + (size_t)b * DD_);
        float acc = 0.f;
        #pragma unroll 8
        for (int j = 0; j < 32; j++) {
            int i4 = kg + j * 8;
            float4 wv = w[i4], xv = x[i4];
            acc += wv.x * xv.x + wv.y * xv.y + wv.z * xv.z + wv.w * xv.w;
        }
        acc += __shfl_xor(acc, 1, 64);
        acc += __shfl_xor(acc, 2, 64);
        acc += __shfl_xor(acc, 4, 64);
        if (kg == 0) pdec[b * A_ + a] = acc + att_b[a];
    } else {
        int idx = (bx - 192) * 256 + tid;               // float4 index
        if (idx < (B_ * DE_ + B_) / 4 + 1)              // 16416 floats
            ((float4*)ctx_un)[idx] = make_float4(0.f, 0.f, 0.f, 0.f);
    }
}

// ---------------------------------------------------------------------------
// Kernel 2: score + context partials. One block = (b, 64 t-rows).
// Conv is computed register-direct in the MFMA fragment mapping: lane
// (wv,col,grp) computes loc[rowb][grp*8..+8] with 1 b32 + 2 broadcast b128
// LDS reads per tap (vs ~16x more scalar reads in the old row-major loop),
// feeding the loc-MFMA A-fragment straight from registers (no loc_s).
// B staged by ping-pong global_load_lds w/ XOR swizzle; A rows from global
// fp32. Max-free softmax (M = sum|out_w|); fused ctx partial + denom.
// ---------------------------------------------------------------------------
__global__ __launch_bounds__(256, 4) void score_kernel(
    const float* __restrict__ input_enc, const __bf16* __restrict__ enc_bf,
    const float* __restrict__ prev_att,  const float* __restrict__ conv_w,
    const __bf16* __restrict__ att_bf,   const float* __restrict__ pdec,
    const float* __restrict__ out_w,     const int* __restrict__ lengths,
    float* __restrict__ wbuf, float* __restrict__ ctx_un,
    float* __restrict__ denom)
{
    __shared__ __align__(16) char Bt[16384];     // 2 halves x (128 rows x 32 k bf16)
    __shared__ __align__(16) float cw_s[KW_ * FN_];   // [k][f] transposed
    __shared__ float pa_s[BT + 2 * FS_];
    __shared__ __align__(16) float w_s[BT];

    const int tid = threadIdx.x;
    const int b  = blockIdx.y;
    const int t0 = blockIdx.x * BT;
    const int len = lengths[b];

    // ---- early exit: fully masked block -> w = 0 for all rows ----
    if (t0 >= len) {
        int t = t0 + tid;
        if (tid < BT && t < T_) wbuf[b * T_ + t] = 0.f;
        return;
    }

    const int lane = tid & 63;
    const int wv   = tid >> 6;
    const int col  = lane & 15;
    const int grp  = lane >> 4;
    const int rowb = wv * 16 + col;
    const int t_row = t0 + rowb;
    const int t_clamp = t_row < T_ ? t_row : T_ - 1;
    const float* arow = input_enc + ((size_t)(b * T_ + t_clamp)) * DE_ + grp * 8;

    // ---- issue chunk-0 staging + A prefetch immediately ----
    // stage: slot s covers row r = s>>2, phys 16B-chunk cp = s&3;
    // source logical chunk c = cp ^ (r&3)  (XOR bank swizzle)
    #pragma unroll
    for (int j = 0; j < 2; j++) {
        int s  = j * 256 + tid;
        int r  = s >> 2;
        int c  = (s & 3) ^ (r & 3);
        load_lds16(enc_bf + (size_t)r * DE_ + c * 8,
                   Bt + j * 4096 + wv * 1024);
    }
    float4 p0 = *(const float4*)(arow);
    float4 p1 = *(const float4*)(arow + 4);

    for (int j = tid; j < BT + 2 * FS_; j += 256) {
        int t = t0 - FS_ + j;
        pa_s[j] = (t >= 0 && t < T_) ? prev_att[b * T_ + t] : 0.f;
    }
    for (int idx = tid; idx < FN_ * KW_; idx += 256) {
        int f = idx / KW_, k = idx % KW_;
        cw_s[k * FN_ + f] = conv_w[idx];
    }
    __syncthreads();

    // ---- conv, register-direct in fragment mapping ----
    float cf[8] = {0.f,0.f,0.f,0.f,0.f,0.f,0.f,0.f};
    #pragma unroll
    for (int k = 0; k < KW_; k++) {
        float pa = pa_s[rowb + k];
        float4 c0 = *(const float4*)(cw_s + k * FN_ + grp * 8);
        float4 c1 = *(const float4*)(cw_s + k * FN_ + grp * 8 + 4);
        cf[0] += pa * c0.x; cf[1] += pa * c0.y; cf[2] += pa * c0.z; cf[3] += pa * c0.w;
        cf[4] += pa * c1.x; cf[5] += pa * c1.y; cf[6] += pa * c1.z; cf[7] += pa * c1.w;
    }

    f32x4 acc[8];
    const f32x4 zero = (f32x4){0.f, 0.f, 0.f, 0.f};

    {   // loc-projection MFMA (K=32=FN), A-frag from conv registers
        bf16x8 afrag;
        #pragma unroll
        for (int j = 0; j < 8; j++) afrag[j] = (__bf16)cf[j];
        #pragma unroll
        for (int i = 0; i < 8; i++) {
            bf16x8 bfrag = *(const bf16x8*)(att_bf + (size_t)(i * 16 + col) * FN_ + grp * 8);
            acc[i] = __builtin_amdgcn_mfma_f32_16x16x32_bf16(afrag, bfrag, zero, 0, 0, 0);
        }
    }

    const int dsoff = (grp ^ (col & 3)) * 16;    // swizzled phys chunk for reads

    #pragma unroll
    for (int k = 0; k < 16; k++) {
        __syncthreads();                          // half(k&1) staged; prior reads done
        float4 n0, n1;
        if (k < 15) {
            int kc_next = (k + 1) * 32;
            char* half = Bt + (((k + 1) & 1) << 13);
            #pragma unroll
            for (int j = 0; j < 2; j++) {
                int s  = j * 256 + tid;
                int r  = s >> 2;
                int c  = (s & 3) ^ (r & 3);
                load_lds16(enc_bf + (size_t)r * DE_ + kc_next + c * 8,
                           half + j * 4096 + wv * 1024);
            }
            n0 = *(const float4*)(arow + kc_next);
            n1 = *(const float4*)(arow + kc_next + 4);
        }
        bf16x8 af;
        af[0] = (__bf16)p0.x; af[1] = (__bf16)p0.y;
        af[2] = (__bf16)p0.z; af[3] = (__bf16)p0.w;
        af[4] = (__bf16)p1.x; af[5] = (__bf16)p1.y;
        af[6] = (__bf16)p1.z; af[7] = (__bf16)p1.w;
        const char* half = Bt + ((k & 1) << 13);
        #pragma unroll
        for (int i = 0; i < 8; i++) {
            bf16x8 bfrag = *(const bf16x8*)(half + (i * 16 + col) * 64 + dsoff);
            acc[i] = __builtin_amdgcn_mfma_f32_16x16x32_bf16(af, bfrag, acc[i], 0, 0, 0);
        }
        p0 = n0; p1 = n1;
    }

    // epilogue: s = tanh(acc + bias) . out_w over a; M = sum|out_w|
    float s[4] = {0.f, 0.f, 0.f, 0.f};
    float Mabs = 0.f;
    #pragma unroll
    for (int i = 0; i < 8; i++) {
        int a = i * 16 + col;
        float ow = out_w[a];
        Mabs += fabsf(ow);
        float bias = pdec[b * A_ + a];
        #pragma unroll
        for (int r = 0; r < 4; r++) {
            float v = acc[i][r] + bias;
            v = fminf(fmaxf(v, -15.f), 15.f);
            float e = __expf(2.f * v);
            s[r] += ow * ((e - 1.f) / (e + 1.f));
        }
    }
    #pragma unroll
    for (int r = 0; r < 4; r++) {
        s[r] += __shfl_xor(s[r], 1, 64);
        s[r] += __shfl_xor(s[r], 2, 64);
        s[r] += __shfl_xor(s[r], 4, 64);
        s[r] += __shfl_xor(s[r], 8, 64);
    }
    Mabs += __shfl_xor(Mabs, 1, 64);
    Mabs += __shfl_xor(Mabs, 2, 64);
    Mabs += __shfl_xor(Mabs, 4, 64);
    Mabs += __shfl_xor(Mabs, 8, 64);    // same value & rounding in every wave

    if (col == 0) {
        int tb = wv * 16 + grp * 4;              // block-local, multiple of 4
        float4 wvec;
        float* wp = &wvec.x;
        #pragma unroll
        for (int r = 0; r < 4; r++) {
            int t = t0 + tb + r;
            wp[r] = (t < len) ? __expf(s[r] - Mabs) : 0.f;
        }
        *(float4*)(w_s + tb) = wvec;
        if (t0 + tb < T_) *(float4*)(wbuf + b * T_ + t0 + tb) = wvec;
    }
    __syncthreads();

    // denominator partial (wave 0)
    if (tid < 64) {
        float w = w_s[tid];
        w += __shfl_xor(w, 1, 64);
        w += __shfl_xor(w, 2, 64);
        w += __shfl_xor(w, 4, 64);
        w += __shfl_xor(w, 8, 64);
        w += __shfl_xor(w, 16, 64);
        w += __shfl_xor(w, 32, 64);
        if (tid == 0) atomicAdd(&denom[b], w);
    }

    // context partial (tile rows L2/L3-hot from the GEMM reads)
    int n_eff = len - t0;
    if (n_eff > BT) n_eff = BT;
    {
        int tg = tid >> 7;                       // 0,1: interleaved t-halves
        int d0 = (tid & 127) * 4;
        const float* ebase = input_enc + ((size_t)(b * T_ + t0)) * DE_ + d0;
        float cx = 0.f, cy = 0.f, cz = 0.f, cw = 0.f;
        #pragma unroll 4
        for (int t = tg; t < n_eff; t += 2) {
            float w = w_s[t];
            float4 v = *(const float4*)(ebase + (size_t)t * DE_);
            cx += w * v.x; cy += w * v.y; cz += w * v.z; cw += w * v.w;
        }
        atomicAdd(&ctx_un[b * DE_ + d0 + 0], cx);
        atomicAdd(&ctx_un[b * DE_ + d0 + 1], cy);
        atomicAdd(&ctx_un[b * DE_ + d0 + 2], cz);
        atomicAdd(&ctx_un[b * DE_ + d0 + 3], cw);
    }
}

// ---------------------------------------------------------------------------
// Kernel 3: finalize. blocks 0..63: att = wbuf/denom; 64..79: ctx = ctx_un/denom
// ---------------------------------------------------------------------------
__global__ __launch_bounds__(256) void finalize_kernel(
    const float* __restrict__ wbuf, const float* __restrict__ ctx_un,
    const float* __restrict__ denom, float* __restrict__ out)
{
    int bx = blockIdx.x, tid = threadIdx.x;
    if (bx < 64) {
        int i4 = bx * 256 + tid;
        if (i4 < (B_ * T_) / 4) {
            int b = i4 / (T_ / 4);
            float inv = 1.f / denom[b];
            float4 w = ((const float4*)wbuf)[i4];
            w.x *= inv; w.y *= inv; w.z *= inv; w.w *= inv;
            ((float4*)(out + B_ * DE_))[i4] = w;
        }
    } else {
        int j = (bx - 64) * 256 + tid;          // 0..4095
        int b = j / (DE_ / 4);
        float inv = 1.f / denom[b];
        float4 c = ((const float4*)ctx_un)[j];
        c.x *= inv; c.y *= inv; c.z *= inv; c.w *= inv;
        ((float4*)out)[j] = c;
    }
}

// ---------------------------------------------------------------------------
extern "C" void kernel_launch(void* const* d_in, const int* in_sizes, int n_in,
                              void* d_out, int out_size, void* d_ws, size_t ws_size,
                              hipStream_t stream)
{
    const float* input_enc   = (const float*)d_in[0];
    const int*   enc_lengths = (const int*)d_in[1];
    const float* input_dec   = (const float*)d_in[2];
    const float* prev_att    = (const float*)d_in[3];
    const float* conv_w      = (const float*)d_in[4];
    const float* enc_w       = (const float*)d_in[5];
    const float* dec_w       = (const float*)d_in[6];
    const float* att_w       = (const float*)d_in[7];
    const float* att_b       = (const float*)d_in[8];
    const float* out_w       = (const float*)d_in[9];

    float* out = (float*)d_out;                 // [0:B*DE) context, [B*DE:) att_weight
    char* ws = (char*)d_ws;
    float*  pdec   = (float*)ws;                              // 4096 f   (16384 B)
    float*  wbuf   = (float*)(ws + 16384);                    // 64000 f  (256000 B)
    __bf16* enc_bf = (__bf16*)(ws + 272384);                  // A*DE bf16 (131072 B)
    __bf16* att_bf = (__bf16*)(ws + 403456);                  // A*FN bf16 (8192 B)
    float*  ctx_un = (float*)(ws + 411648);                   // 16384 f  (65536 B)
    float*  denom  = (float*)(ws + 477184);                   // 32 f (contiguous w/ ctx_un)

    prep_kernel<<<209, 256, 0, stream>>>(enc_w, att_w, input_dec, dec_w, att_b,
                                         enc_bf, att_bf, pdec, ctx_un);

    dim3 sgrid((T_ + BT - 1) / BT, B_);
    score_kernel<<<sgrid, 256, 0, stream>>>(input_enc, enc_bf, prev_att, conv_w,
                                            att_bf, pdec, out_w, enc_lengths,
                                            wbuf, ctx_un, denom);

    finalize_kernel<<<80, 256, 0, stream>>>(wbuf, ctx_un, denom, out);
}

// Round 7
// 227.188 us; speedup vs baseline: 1.0034x; 1.0003x over previous
//
#include <hip/hip_runtime.h>
#include <hip/hip_bf16.h>
#include <math.h>

#define B_ 32
#define T_ 2000
#define DE_ 512
#define DD_ 1024
#define A_ 128
#define FN_ 32
#define FS_ 16
#define KW_ (2*FS_+1)   // 33

typedef __bf16 bf16x8 __attribute__((ext_vector_type(8)));
typedef __bf16 bf16x4 __attribute__((ext_vector_type(4)));
typedef float f32x4 __attribute__((ext_vector_type(4)));

#define BT 128           // t-rows per score block (2 row-groups of 64)

// async global->LDS, 16 B per lane; dest = lds base (wave-uniform) + lane*16
__device__ __forceinline__ void load_lds16(const void* g, void* l) {
    __builtin_amdgcn_global_load_lds(
        (const __attribute__((address_space(1))) unsigned int*)g,
        (__attribute__((address_space(3))) unsigned int*)l, 16, 0, 0);
}

// ---------------------------------------------------------------------------
// Kernel 1: prep.
//  blocks   0..63 : enc_w/att_w fp32->bf16
//  blocks  64..191: pdec[b][a] = att_b[a] + input_dec[b] . dec_w[a]
//  blocks 192..208: zero ctx_un (16384 f) + denom (32 f)
// ---------------------------------------------------------------------------
__global__ __launch_bounds__(256) void prep_kernel(
    const float* __restrict__ enc_w, const float* __restrict__ att_w,
    const float* __restrict__ input_dec, const float* __restrict__ dec_w,
    const float* __restrict__ att_b,
    __bf16* __restrict__ enc_bf, __bf16* __restrict__ att_bf,
    float* __restrict__ pdec, float* __restrict__ ctx_un /* denom follows */)
{
    int bx = blockIdx.x, tid = threadIdx.x;
    if (bx < 64) {
        int i = bx * 256 + tid;                         // float4 index
        float4 v = ((const float4*)enc_w)[i];
        bf16x4 o;
        o[0] = (__bf16)v.x; o[1] = (__bf16)v.y; o[2] = (__bf16)v.z; o[3] = (__bf16)v.w;
        *(bf16x4*)(enc_bf + (size_t)i * 4) = o;
        if (i < (A_ * FN_) / 4) {
            float4 w = ((const float4*)att_w)[i];
            bf16x4 p;
            p[0] = (__bf16)w.x; p[1] = (__bf16)w.y; p[2] = (__bf16)w.z; p[3] = (__bf16)w.w;
            *(bf16x4*)(att_bf + (size_t)i * 4) = p;
        }
    } else if (bx < 192) {
        int pb = bx - 64;                               // 0..127
        int b  = pb >> 2;
        int a0 = (pb & 3) * 32;
        int al = tid >> 3;                              // 0..31
        int kg = tid & 7;                               // 0..7
        int a  = a0 + al;
        const float4* w = (const float4*)(dec_w + (size_t)a * DD_);
        const float4* x = (const float4*)(input_dec + (size_t)b * DD_);
        float acc = 0.f;
        #pragma unroll 8
        for (int j = 0; j < 32; j++) {
            int i4 = kg + j * 8;
            float4 wv = w[i4], xv = x[i4];
            acc += wv.x * xv.x + wv.y * xv.y + wv.z * xv.z + wv.w * xv.w;
        }
        acc += __shfl_xor(acc, 1, 64);
        acc += __shfl_xor(acc, 2, 64);
        acc += __shfl_xor(acc, 4, 64);
        if (kg == 0) pdec[b * A_ + a] = acc + att_b[a];
    } else {
        int idx = (bx - 192) * 256 + tid;               // float4 index
        if (idx < (B_ * DE_ + B_) / 4 + 1)              // 16416 floats
            ((float4*)ctx_un)[idx] = make_float4(0.f, 0.f, 0.f, 0.f);
    }
}

// ---------------------------------------------------------------------------
// Kernel 2: score + context partials. One block = (b, 128 t-rows): each lane
// carries TWO accumulator streams (rows rowb and rowb+64) to amortize all
// per-block fixed costs (prologue, conv, barriers, epilogue, ctx) over 2x
// rows and double per-wave ILP. K-chunk = 64 (two 32-k sub-chunks staged
// per barrier, ping-pong 2x16 KB) -> 8 barriers/block. Sub-chunk LDS layout
// + XOR swizzle identical to the proven BT=64 version. Max-free softmax
// (M = sum|out_w|); fused ctx partial + denom.
// ---------------------------------------------------------------------------
__global__ __launch_bounds__(256, 2) void score_kernel(
    const float* __restrict__ input_enc, const __bf16* __restrict__ enc_bf,
    const float* __restrict__ prev_att,  const float* __restrict__ conv_w,
    const __bf16* __restrict__ att_bf,   const float* __restrict__ pdec,
    const float* __restrict__ out_w,     const int* __restrict__ lengths,
    float* __restrict__ wbuf, float* __restrict__ ctx_un,
    float* __restrict__ denom)
{
    __shared__ __align__(16) char Bt[32768];     // 2 chunk-bufs x 2 sub-chunks x 8 KB
    __shared__ __align__(16) float cw_s[KW_ * FN_];   // [k][f] transposed
    __shared__ float pa_s[BT + 2 * FS_];
    __shared__ __align__(16) float w_s[BT];

    const int tid = threadIdx.x;
    const int b  = blockIdx.y;
    const int t0 = blockIdx.x * BT;
    const int len = lengths[b];

    // ---- early exit: fully masked block -> w = 0 for all rows ----
    if (t0 >= len) {
        if (tid < BT) {
            int t = t0 + tid;
            if (t < T_) wbuf[b * T_ + t] = 0.f;
        }
        return;
    }

    const int lane = tid & 63;
    const int wv   = tid >> 6;
    const int col  = lane & 15;
    const int grp  = lane >> 4;
    const int rowb = wv * 16 + col;              // row-group 0 row; group 1 = +64
    const int tc0 = (t0 + rowb) < T_ ? (t0 + rowb) : T_ - 1;
    const int tc1 = (t0 + rowb + 64) < T_ ? (t0 + rowb + 64) : T_ - 1;
    const float* arow0 = input_enc + ((size_t)(b * T_ + tc0)) * DE_ + grp * 8;
    const float* arow1 = input_enc + ((size_t)(b * T_ + tc1)) * DE_ + grp * 8;

    // ---- stage chunk 0 (2 sub-chunks, 16 KB) + A prefetch ----
    // sub-chunk slot s (0..511): row r = s>>2, phys 16B-chunk cp = s&3,
    // source logical chunk c = cp ^ (r&3)  (XOR bank swizzle)
    #pragma unroll
    for (int j = 0; j < 2; j++) {                // sub-chunk
        #pragma unroll
        for (int m = 0; m < 2; m++) {            // round
            int s = m * 256 + tid;
            int r = s >> 2;
            int c = (s & 3) ^ (r & 3);
            load_lds16(enc_bf + (size_t)r * DE_ + j * 32 + c * 8,
                       Bt + j * 8192 + m * 4096 + wv * 1024);
        }
    }
    float4 a0p[4], a1p[4];
    #pragma unroll
    for (int j = 0; j < 2; j++) {
        a0p[2*j]   = *(const float4*)(arow0 + j * 32);
        a0p[2*j+1] = *(const float4*)(arow0 + j * 32 + 4);
        a1p[2*j]   = *(const float4*)(arow1 + j * 32);
        a1p[2*j+1] = *(const float4*)(arow1 + j * 32 + 4);
    }

    for (int j = tid; j < BT + 2 * FS_; j += 256) {
        int t = t0 - FS_ + j;
        pa_s[j] = (t >= 0 && t < T_) ? prev_att[b * T_ + t] : 0.f;
    }
    for (int idx = tid; idx < FN_ * KW_; idx += 256) {
        int f = idx / KW_, k = idx % KW_;
        cw_s[k * FN_ + f] = conv_w[idx];
    }
    __syncthreads();

    // ---- conv for both rows, register-direct in fragment mapping ----
    float cf0[8] = {0,0,0,0,0,0,0,0}, cf1[8] = {0,0,0,0,0,0,0,0};
    #pragma unroll
    for (int k = 0; k < KW_; k++) {
        float paA = pa_s[rowb + k];
        float paB = pa_s[rowb + 64 + k];
        float4 c0 = *(const float4*)(cw_s + k * FN_ + grp * 8);
        float4 c1 = *(const float4*)(cw_s + k * FN_ + grp * 8 + 4);
        cf0[0] += paA * c0.x; cf0[1] += paA * c0.y; cf0[2] += paA * c0.z; cf0[3] += paA * c0.w;
        cf0[4] += paA * c1.x; cf0[5] += paA * c1.y; cf0[6] += paA * c1.z; cf0[7] += paA * c1.w;
        cf1[0] += paB * c0.x; cf1[1] += paB * c0.y; cf1[2] += paB * c0.z; cf1[3] += paB * c0.w;
        cf1[4] += paB * c1.x; cf1[5] += paB * c1.y; cf1[6] += paB * c1.z; cf1[7] += paB * c1.w;
    }

    f32x4 acc0[8], acc1[8];
    const f32x4 zero = (f32x4){0.f, 0.f, 0.f, 0.f};

    {   // loc-projection MFMA (K=32=FN), A-frags from conv registers
        bf16x8 af0, af1;
        #pragma unroll
        for (int j = 0; j < 8; j++) { af0[j] = (__bf16)cf0[j]; af1[j] = (__bf16)cf1[j]; }
        #pragma unroll
        for (int i = 0; i < 8; i++) {
            bf16x8 bfrag = *(const bf16x8*)(att_bf + (size_t)(i * 16 + col) * FN_ + grp * 8);
            acc0[i] = __builtin_amdgcn_mfma_f32_16x16x32_bf16(af0, bfrag, zero, 0, 0, 0);
            acc1[i] = __builtin_amdgcn_mfma_f32_16x16x32_bf16(af1, bfrag, zero, 0, 0, 0);
        }
    }

    const int dsoff = (grp ^ (col & 3)) * 16;    // swizzled phys chunk for reads

    #pragma unroll
    for (int k = 0; k < 8; k++) {                // K chunks of 64
        __syncthreads();                          // chunk k staged; prior reads done
        float4 n0[4], n1[4];
        if (k < 7) {
            int kc_next = (k + 1) * 64;
            char* buf = Bt + (((k + 1) & 1) << 14);
            #pragma unroll
            for (int j = 0; j < 2; j++) {
                #pragma unroll
                for (int m = 0; m < 2; m++) {
                    int s = m * 256 + tid;
                    int r = s >> 2;
                    int c = (s & 3) ^ (r & 3);
                    load_lds16(enc_bf + (size_t)r * DE_ + kc_next + j * 32 + c * 8,
                               buf + j * 8192 + m * 4096 + wv * 1024);
                }
            }
            #pragma unroll
            for (int j = 0; j < 2; j++) {
                n0[2*j]   = *(const float4*)(arow0 + kc_next + j * 32);
                n0[2*j+1] = *(const float4*)(arow0 + kc_next + j * 32 + 4);
                n1[2*j]   = *(const float4*)(arow1 + kc_next + j * 32);
                n1[2*j+1] = *(const float4*)(arow1 + kc_next + j * 32 + 4);
            }
        }
        const char* buf = Bt + ((k & 1) << 14);
        #pragma unroll
        for (int j = 0; j < 2; j++) {            // sub-chunk (K=32 each)
            bf16x8 af0, af1;
            float* p;
            p = &a0p[2*j].x;
            #pragma unroll
            for (int q = 0; q < 8; q++) af0[q] = (__bf16)p[q];
            p = &a1p[2*j].x;
            #pragma unroll
            for (int q = 0; q < 8; q++) af1[q] = (__bf16)p[q];
            const char* sub = buf + j * 8192;
            #pragma unroll
            for (int i = 0; i < 8; i++) {
                bf16x8 bfrag = *(const bf16x8*)(sub + (i * 16 + col) * 64 + dsoff);
                acc0[i] = __builtin_amdgcn_mfma_f32_16x16x32_bf16(af0, bfrag, acc0[i], 0, 0, 0);
                acc1[i] = __builtin_amdgcn_mfma_f32_16x16x32_bf16(af1, bfrag, acc1[i], 0, 0, 0);
            }
        }
        #pragma unroll
        for (int q = 0; q < 4; q++) { a0p[q] = n0[q]; a1p[q] = n1[q]; }
    }

    // epilogue: s = tanh(acc + bias) . out_w over a; M = sum|out_w|
    float s0[4] = {0,0,0,0}, s1[4] = {0,0,0,0};
    float Mabs = 0.f;
    #pragma unroll
    for (int i = 0; i < 8; i++) {
        int a = i * 16 + col;
        float ow = out_w[a];
        Mabs += fabsf(ow);
        float bias = pdec[b * A_ + a];
        #pragma unroll
        for (int r = 0; r < 4; r++) {
            float v0 = acc0[i][r] + bias;
            v0 = fminf(fmaxf(v0, -15.f), 15.f);
            float e0 = __expf(2.f * v0);
            s0[r] += ow * ((e0 - 1.f) / (e0 + 1.f));
            float v1 = acc1[i][r] + bias;
            v1 = fminf(fmaxf(v1, -15.f), 15.f);
            float e1 = __expf(2.f * v1);
            s1[r] += ow * ((e1 - 1.f) / (e1 + 1.f));
        }
    }
    #pragma unroll
    for (int r = 0; r < 4; r++) {
        #pragma unroll
        for (int off = 1; off < 16; off <<= 1) {
            s0[r] += __shfl_xor(s0[r], off, 64);
            s1[r] += __shfl_xor(s1[r], off, 64);
        }
    }
    Mabs += __shfl_xor(Mabs, 1, 64);
    Mabs += __shfl_xor(Mabs, 2, 64);
    Mabs += __shfl_xor(Mabs, 4, 64);
    Mabs += __shfl_xor(Mabs, 8, 64);    // same value & rounding in every wave

    if (col == 0) {
        int tb = wv * 16 + grp * 4;              // block-local, multiple of 4
        float4 wv0, wv1;
        float *p0 = &wv0.x, *p1 = &wv1.x;
        #pragma unroll
        for (int r = 0; r < 4; r++) {
            int tA = t0 + tb + r;
            int tB = tA + 64;
            p0[r] = (tA < len) ? __expf(s0[r] - Mabs) : 0.f;
            p1[r] = (tB < len) ? __expf(s1[r] - Mabs) : 0.f;
        }
        *(float4*)(w_s + tb) = wv0;
        *(float4*)(w_s + tb + 64) = wv1;
        if (t0 + tb < T_)      *(float4*)(wbuf + b * T_ + t0 + tb) = wv0;
        if (t0 + tb + 64 < T_) *(float4*)(wbuf + b * T_ + t0 + tb + 64) = wv1;
    }
    __syncthreads();

    // denominator partial (wave 0)
    if (tid < 64) {
        float w = w_s[tid] + w_s[tid + 64];
        #pragma unroll
        for (int off = 1; off < 64; off <<= 1) w += __shfl_xor(w, off, 64);
        if (tid == 0) atomicAdd(&denom[b], w);
    }

    // context partial (tile rows L2/L3-hot from the GEMM reads)
    int n_eff = len - t0;
    if (n_eff > BT) n_eff = BT;
    {
        int tg = tid >> 7;                       // 0,1: interleaved t-halves
        int d0 = (tid & 127) * 4;
        const float* ebase = input_enc + ((size_t)(b * T_ + t0)) * DE_ + d0;
        float cx = 0.f, cy = 0.f, cz = 0.f, cw = 0.f;
        #pragma unroll 4
        for (int t = tg; t < n_eff; t += 2) {
            float w = w_s[t];
            float4 v = *(const float4*)(ebase + (size_t)t * DE_);
            cx += w * v.x; cy += w * v.y; cz += w * v.z; cw += w * v.w;
        }
        atomicAdd(&ctx_un[b * DE_ + d0 + 0], cx);
        atomicAdd(&ctx_un[b * DE_ + d0 + 1], cy);
        atomicAdd(&ctx_un[b * DE_ + d0 + 2], cz);
        atomicAdd(&ctx_un[b * DE_ + d0 + 3], cw);
    }
}

// ---------------------------------------------------------------------------
// Kernel 3: finalize. blocks 0..63: att = wbuf/denom; 64..79: ctx = ctx_un/denom
// ---------------------------------------------------------------------------
__global__ __launch_bounds__(256) void finalize_kernel(
    const float* __restrict__ wbuf, const float* __restrict__ ctx_un,
    const float* __restrict__ denom, float* __restrict__ out)
{
    int bx = blockIdx.x, tid = threadIdx.x;
    if (bx < 64) {
        int i4 = bx * 256 + tid;
        if (i4 < (B_ * T_) / 4) {
            int b = i4 / (T_ / 4);
            float inv = 1.f / denom[b];
            float4 w = ((const float4*)wbuf)[i4];
            w.x *= inv; w.y *= inv; w.z *= inv; w.w *= inv;
            ((float4*)(out + B_ * DE_))[i4] = w;
        }
    } else {
        int j = (bx - 64) * 256 + tid;          // 0..4095
        int b = j / (DE_ / 4);
        float inv = 1.f / denom[b];
        float4 c = ((const float4*)ctx_un)[j];
        c.x *= inv; c.y *= inv; c.z *= inv; c.w *= inv;
        ((float4*)out)[j] = c;
    }
}

// ---------------------------------------------------------------------------
extern "C" void kernel_launch(void* const* d_in, const int* in_sizes, int n_in,
                              void* d_out, int out_size, void* d_ws, size_t ws_size,
                              hipStream_t stream)
{
    const float* input_enc   = (const float*)d_in[0];
    const int*   enc_lengths = (const int*)d_in[1];
    const float* input_dec   = (const float*)d_in[2];
    const float* prev_att    = (const float*)d_in[3];
    const float* conv_w      = (const float*)d_in[4];
    const float* enc_w       = (const float*)d_in[5];
    const float* dec_w       = (const float*)d_in[6];
    const float* att_w       = (const float*)d_in[7];
    const float* att_b       = (const float*)d_in[8];
    const float* out_w       = (const float*)d_in[9];

    float* out = (float*)d_out;                 // [0:B*DE) context, [B*DE:) att_weight
    char* ws = (char*)d_ws;
    float*  pdec   = (float*)ws;                              // 4096 f   (16384 B)
    float*  wbuf   = (float*)(ws + 16384);                    // 64000 f  (256000 B)
    __bf16* enc_bf = (__bf16*)(ws + 272384);                  // A*DE bf16 (131072 B)
    __bf16* att_bf = (__bf16*)(ws + 403456);                  // A*FN bf16 (8192 B)
    float*  ctx_un = (float*)(ws + 411648);                   // 16384 f  (65536 B)
    float*  denom  = (float*)(ws + 477184);                   // 32 f (contiguous w/ ctx_un)

    prep_kernel<<<209, 256, 0, stream>>>(enc_w, att_w, input_dec, dec_w, att_b,
                                         enc_bf, att_bf, pdec, ctx_un);

    dim3 sgrid((T_ + BT - 1) / BT, B_);
    score_kernel<<<sgrid, 256, 0, stream>>>(input_enc, enc_bf, prev_att, conv_w,
                                            att_bf, pdec, out_w, enc_lengths,
                                            wbuf, ctx_un, denom);

    finalize_kernel<<<80, 256, 0, stream>>>(wbuf, ctx_un, denom, out);
}